// Round 7
// baseline (392.246 us; speedup 1.0000x reference)
//
#include <hip/hip_runtime.h>
#include <stdint.h>

#define LAMBDA_INIT_F 0.7836057665f   // 0.8 - 0.6*exp(-0.3*12)

typedef __bf16 bf16x8 __attribute__((ext_vector_type(8)));
typedef float  f32x4  __attribute__((ext_vector_type(4)));
typedef unsigned short u16x8 __attribute__((ext_vector_type(8)));
typedef unsigned short u16x4 __attribute__((ext_vector_type(4)));
typedef unsigned int u32x4 __attribute__((ext_vector_type(4)));

__device__ __forceinline__ unsigned short f2b(float f) {
    union { float f; unsigned u; } v; v.f = f;
    unsigned u = v.u;
    return (unsigned short)((u + 0x7fffu + ((u >> 16) & 1u)) >> 16);
}

// pack two fp32 -> two bf16 (round-half-up) in one dword: [bf(b):bf(a)]
__device__ __forceinline__ unsigned pk2(float a, float b) {
    unsigned ua = __float_as_uint(a) + 0x8000u;
    unsigned ub = __float_as_uint(b) + 0x8000u;
    return __builtin_amdgcn_perm(ub, ua, 0x07060302u);
}

#if __has_builtin(__builtin_amdgcn_exp2f)
#define EXP2(x) __builtin_amdgcn_exp2f(x)
#else
__device__ __forceinline__ float EXP2(float x) {
    float r; asm volatile("v_exp_f32 %0, %1\n\ts_nop 1" : "=v"(r) : "v"(x)); return r;
}
#endif

// global(16B/lane) -> LDS direct. LDS base must be wave-uniform; lanes land at base + lane*16.
#define GLD16(gp, sp) __builtin_amdgcn_global_load_lds( \
    (const __attribute__((address_space(1))) void*)(uintptr_t)(gp), \
    (__attribute__((address_space(3))) void*)(uint32_t)(uintptr_t)(sp), 16, 0, 0)

// ---------------- fp32 -> bf16 convert (now only used for Wo, 1 slab) ----------------
__global__ __launch_bounds__(256) void cvt7(const float* __restrict__ s0, const float* __restrict__ s1,
                                            const float* __restrict__ s2, const float* __restrict__ s3,
                                            const float* __restrict__ s4, const float* __restrict__ s5,
                                            const float* __restrict__ s6,
                                            unsigned short* __restrict__ dst) {
    int z = blockIdx.y;
    const float* s = z == 0 ? s0 : z == 1 ? s1 : z == 2 ? s2 : z == 3 ? s3 : z == 4 ? s4 : z == 5 ? s5 : s6;
    unsigned short* d = dst + (size_t)z * 4194304;
    size_t i = ((size_t)blockIdx.x * 256 + threadIdx.x) * 8;
    float4 a = *(const float4*)(s + i);
    float4 b = *(const float4*)(s + i + 4);
    u16x8 o;
    o[0] = f2b(a.x); o[1] = f2b(a.y); o[2] = f2b(a.z); o[3] = f2b(a.w);
    o[4] = f2b(b.x); o[5] = f2b(b.y); o[6] = f2b(b.z); o[7] = f2b(b.w);
    *(u16x8*)(d + i) = o;
}

// ---------------- QKV projection: 256x256 tile, BK=64, 8 waves, 4-phase, f32 reg-staging ----------
// C = alpha * X(2048x2048,f32) @ W(2048x2048,f32)^T per z; z==2 writes C^T to VT (pi-permuted kv).
// Staging converts f32->bf16 in-flight (kills the separate cvt pass): per 16B LDS unit,
// 2x float4 from the SAME swizzled source column as the old GLD16 path -> pk2 pack ->
// one linear ds_write_b128. LDS image is bit-identical to round 6 (conflict-free).
// Loads for tile kt+1 issue at P1 (T14 issue-early); writes land in the dead regions at
// P2 (Ah0,Bh0), P3 (Bh1), P4 (Ah1); compiler value-deps give counted-vmcnt semantics.
__global__ __launch_bounds__(512, 2) void gemm_qkv(const float* __restrict__ Qf, const float* __restrict__ Kf,
                                                   const float* __restrict__ Vf, const float* __restrict__ Wqf,
                                                   const float* __restrict__ Wkf, const float* __restrict__ Wvf,
                                                   unsigned short* __restrict__ Cb,
                                                   unsigned short* __restrict__ VT,
                                                   float alpha0) {
    __shared__ __align__(16) unsigned short As[16384];   // [kk*8192 + row*32 + col], 64B rows
    __shared__ __align__(16) unsigned short Bs[16384];
    const int tid = threadIdx.x;
    const int wid = tid >> 6, lane = tid & 63;
    const int quad = lane >> 4, l16 = lane & 15;
    const int wr = wid >> 2, wc = wid & 3;                 // wave grid 2M x 4N
    const int bid = blockIdx.x;
    const int wrk = (bid & 7) * 24 + (bid >> 3);           // bijective XCD swizzle (192 = 8*24)
    const int z = wrk >> 6;
    const int t6 = wrk & 63;
    const int m0 = (t6 >> 3) * 256, n0 = (t6 & 7) * 256;
    const float* Af = z == 0 ? Qf : z == 1 ? Kf : Vf;
    const float* Bf = z == 0 ? Wqf : z == 1 ? Wkf : Wvf;
    const float alpha = (z == 0) ? alpha0 : 1.0f;

    const int sr = lane >> 2;                              // 0..15 row within 16-row slab
    const int sc = (((lane & 3) ^ ((lane >> 3) & 3)) * 8); // swizzled source colblock (elements)
    const int rsw = ((l16 >> 1) & 3);                      // read-side swizzle key

    f32x4 acc[8][4];
#pragma unroll
    for (int mi = 0; mi < 8; ++mi)
#pragma unroll
        for (int ni = 0; ni < 4; ++ni) acc[mi][ni] = f32x4{0.f, 0.f, 0.f, 0.f};

    // ---- reg-staging helpers: same element indices as the old GLD16 path ----
    auto LOAD_A = [&](int h, int k0, f32x4 (&R)[2][2]) {
        const int rb = (wid >> 2) * 128 + (wid & 3) * 16 + h * 64;
#pragma unroll
        for (int kk = 0; kk < 2; ++kk) {
            const float* p = Af + (size_t)(m0 + rb + sr) * 2048 + k0 + kk * 32 + sc;
            R[kk][0] = *(const f32x4*)p;
            R[kk][1] = *(const f32x4*)(p + 4);
        }
    };
    auto LOAD_B = [&](int h, int k0, f32x4 (&R)[2][2]) {
        const int rb = (wid >> 1) * 64 + (wid & 1) * 16 + h * 32;
#pragma unroll
        for (int kk = 0; kk < 2; ++kk) {
            const float* p = Bf + (size_t)(n0 + rb + sr) * 2048 + k0 + kk * 32 + sc;
            R[kk][0] = *(const f32x4*)p;
            R[kk][1] = *(const f32x4*)(p + 4);
        }
    };
    auto WR_A = [&](int h, f32x4 (&R)[2][2]) {
        const int rb = (wid >> 2) * 128 + (wid & 3) * 16 + h * 64;
#pragma unroll
        for (int kk = 0; kk < 2; ++kk) {
            u32x4 o;
            o[0] = pk2(R[kk][0][0], R[kk][0][1]); o[1] = pk2(R[kk][0][2], R[kk][0][3]);
            o[2] = pk2(R[kk][1][0], R[kk][1][1]); o[3] = pk2(R[kk][1][2], R[kk][1][3]);
            *(u32x4*)&As[(kk * 256 + rb) * 32 + lane * 8] = o;   // lane*16B, linear (matches GLD16 image)
        }
    };
    auto WR_B = [&](int h, f32x4 (&R)[2][2]) {
        const int rb = (wid >> 1) * 64 + (wid & 1) * 16 + h * 32;
#pragma unroll
        for (int kk = 0; kk < 2; ++kk) {
            u32x4 o;
            o[0] = pk2(R[kk][0][0], R[kk][0][1]); o[1] = pk2(R[kk][0][2], R[kk][0][3]);
            o[2] = pk2(R[kk][1][0], R[kk][1][1]); o[3] = pk2(R[kk][1][2], R[kk][1][3]);
            *(u32x4*)&Bs[(kk * 256 + rb) * 32 + lane * 8] = o;
        }
    };

#define LD_A(mh, i, kk) (*(const bf16x8*)&As[(kk * 256 + wr * 128 + (mh) * 64 + (i) * 16 + l16) * 32 + (quad ^ rsw) * 8])
#define LD_B(nh, jn, kk) (*(const bf16x8*)&Bs[(kk * 256 + wc * 64 + (nh) * 32 + (jn) * 16 + l16) * 32 + (quad ^ rsw) * 8])
#define LGKM0 asm volatile("s_waitcnt lgkmcnt(0)" ::: "memory")

    // prologue: stage tile 0 (load -> pack -> write), then barrier
    {
        f32x4 pA0[2][2], pA1[2][2], pB0[2][2], pB1[2][2];
        LOAD_A(0, 0, pA0); LOAD_B(0, 0, pB0); LOAD_B(1, 0, pB1); LOAD_A(1, 0, pA1);
        WR_A(0, pA0); WR_B(0, pB0); WR_B(1, pB1); WR_A(1, pA1);
        LGKM0;
        __builtin_amdgcn_s_barrier();
    }

    for (int kt = 0; kt < 32; ++kt) {
        const int k1 = (kt + 1) * 64;
        bf16x8 af[2][4], b0[2][2], b1[2][2];
        f32x4 nA0[2][2], nA1[2][2], nB0[2][2], nB1[2][2];

        // ---- P1: issue next-tile global loads; ds_read A0,B0; MFMA quadrant (0,0)
        if (kt < 31) { LOAD_A(0, k1, nA0); LOAD_B(0, k1, nB0); LOAD_B(1, k1, nB1); LOAD_A(1, k1, nA1); }
#pragma unroll
        for (int kk = 0; kk < 2; ++kk) {
#pragma unroll
            for (int i = 0; i < 4; ++i) af[kk][i] = LD_A(0, i, kk);
#pragma unroll
            for (int jn = 0; jn < 2; ++jn) b0[kk][jn] = LD_B(0, jn, kk);
        }
        __builtin_amdgcn_s_barrier();
        __builtin_amdgcn_s_setprio(1);
#pragma unroll
        for (int i = 0; i < 4; ++i)
#pragma unroll
            for (int jn = 0; jn < 2; ++jn)
#pragma unroll
                for (int kk = 0; kk < 2; ++kk)
                    acc[i][jn] = __builtin_amdgcn_mfma_f32_16x16x32_bf16(af[kk][i], b0[kk][jn], acc[i][jn], 0, 0, 0);
        __builtin_amdgcn_s_setprio(0);
        __builtin_amdgcn_s_barrier();

        // ---- P2: ds_read B1(kt); pack+write Ah0,Bh0(kt+1) into dead regions; MFMA (0,1)
#pragma unroll
        for (int kk = 0; kk < 2; ++kk)
#pragma unroll
            for (int jn = 0; jn < 2; ++jn) b1[kk][jn] = LD_B(1, jn, kk);
        if (kt < 31) { WR_A(0, nA0); WR_B(0, nB0); }
        LGKM0;
        __builtin_amdgcn_s_barrier();
        __builtin_amdgcn_s_setprio(1);
#pragma unroll
        for (int i = 0; i < 4; ++i)
#pragma unroll
            for (int jn = 0; jn < 2; ++jn)
#pragma unroll
                for (int kk = 0; kk < 2; ++kk)
                    acc[i][2 + jn] = __builtin_amdgcn_mfma_f32_16x16x32_bf16(af[kk][i], b1[kk][jn], acc[i][2 + jn], 0, 0, 0);
        __builtin_amdgcn_s_setprio(0);
        __builtin_amdgcn_s_barrier();

        // ---- P3: ds_read A1(kt); pack+write Bh1(kt+1); MFMA (1,1)
#pragma unroll
        for (int kk = 0; kk < 2; ++kk)
#pragma unroll
            for (int i = 0; i < 4; ++i) af[kk][i] = LD_A(1, i, kk);
        if (kt < 31) WR_B(1, nB1);
        LGKM0;
        __builtin_amdgcn_s_barrier();
        __builtin_amdgcn_s_setprio(1);
#pragma unroll
        for (int i = 0; i < 4; ++i)
#pragma unroll
            for (int jn = 0; jn < 2; ++jn)
#pragma unroll
                for (int kk = 0; kk < 2; ++kk)
                    acc[4 + i][2 + jn] = __builtin_amdgcn_mfma_f32_16x16x32_bf16(af[kk][i], b1[kk][jn], acc[4 + i][2 + jn], 0, 0, 0);
        __builtin_amdgcn_s_setprio(0);
        __builtin_amdgcn_s_barrier();

        // ---- P4: pack+write Ah1(kt+1); register-only MFMA (1,0)
        if (kt < 31) WR_A(1, nA1);
        LGKM0;
        __builtin_amdgcn_s_barrier();
        __builtin_amdgcn_s_setprio(1);
#pragma unroll
        for (int i = 0; i < 4; ++i)
#pragma unroll
            for (int jn = 0; jn < 2; ++jn)
#pragma unroll
                for (int kk = 0; kk < 2; ++kk)
                    acc[4 + i][jn] = __builtin_amdgcn_mfma_f32_16x16x32_bf16(af[kk][i], b0[kk][jn], acc[4 + i][jn], 0, 0, 0);
        __builtin_amdgcn_s_setprio(0);
        __builtin_amdgcn_s_barrier();
    }
#undef LD_A
#undef LD_B
#undef LGKM0

    if (z == 2) {
        // transposed write: VT[n][pi(m)], packed 4 bf16 (m-consecutive, pi keeps low 2 bits)
#pragma unroll
        for (int mi = 0; mi < 8; ++mi)
#pragma unroll
            for (int ni = 0; ni < 4; ++ni) {
                int n = n0 + wc * 64 + ni * 16 + l16;
                int m = m0 + wr * 128 + mi * 16 + quad * 4;
                int sm = (m & ~31) | ((m & 12) << 1) | ((m & 16) >> 2) | (m & 3);
                u16x4 o;
#pragma unroll
                for (int r = 0; r < 4; ++r) o[r] = f2b(acc[mi][ni][r]);
                *(u16x4*)&VT[(size_t)n * 2048 + sm] = o;
            }
    } else {
        unsigned short* Cz = Cb + (size_t)z * 4194304;
#pragma unroll
        for (int mi = 0; mi < 8; ++mi)
#pragma unroll
            for (int ni = 0; ni < 4; ++ni)
#pragma unroll
                for (int r = 0; r < 4; ++r) {
                    int row = m0 + wr * 128 + mi * 16 + quad * 4 + r;
                    int col = n0 + wc * 64 + ni * 16 + l16;
                    Cz[(size_t)row * 2048 + col] = f2b(acc[mi][ni][r] * alpha);
                }
    }
}

// ---------------- output projection: 128x64 tiles, triple-buffered (unchanged) ----------------
template <int OUT_BF16, int NT, int DO_VT, int WPB>
__global__ __launch_bounds__(256, WPB) void gemm_bt(const unsigned short* __restrict__ Abase,
                                                    const unsigned short* __restrict__ Bbase,
                                                    void* __restrict__ Cbase,
                                                    unsigned short* __restrict__ VT,
                                                    float alpha0) {
    constexpr int MI = (NT == 128) ? 4 : 2;
    __shared__ __align__(16) unsigned short As[3][128 * 32];
    __shared__ __align__(16) unsigned short Bs[3][NT * 32];
    const int tid = threadIdx.x;
    const int w = tid >> 6, lane = tid & 63;
    const int quad = lane >> 4, l16 = lane & 15;
    const int b = blockIdx.z;
    const unsigned short* A = Abase + (size_t)b * 4194304;
    const unsigned short* B = Bbase + (size_t)b * 4194304;
    const float alpha = (b == 0) ? alpha0 : 1.0f;
    const int m0 = blockIdx.y * 128, n0 = blockIdx.x * NT;
    const int wm = (NT == 128) ? (w >> 1) * 64 : w * 32;
    const int wn = (NT == 128) ? (w & 1) * 64 : 0;
    const int sr = lane >> 2;                              // 0..15 row within 16-row slab
    const int sc = (((lane & 3) ^ ((lane >> 3) & 3)) * 8); // swizzled global colblock
    const int rsw = ((l16 >> 1) & 3);                      // read-side swizzle key

    f32x4 zz = {0.f, 0.f, 0.f, 0.f};
    f32x4 acc[MI][4];
#pragma unroll
    for (int i = 0; i < MI; ++i)
#pragma unroll
        for (int jn = 0; jn < 4; ++jn) acc[i][jn] = zz;

    auto STAGE = [&](int bsel, int k0) {
        GLD16(A + (size_t)(m0 + w * 16 + sr) * 2048 + k0 + sc,      &As[bsel][(w * 16) * 32]);
        GLD16(A + (size_t)(m0 + 64 + w * 16 + sr) * 2048 + k0 + sc, &As[bsel][(64 + w * 16) * 32]);
        if (NT == 128) {
            GLD16(B + (size_t)(n0 + w * 16 + sr) * 2048 + k0 + sc,      &Bs[bsel][(w * 16) * 32]);
            GLD16(B + (size_t)(n0 + 64 + w * 16 + sr) * 2048 + k0 + sc, &Bs[bsel][(64 + w * 16) * 32]);
        } else {
            GLD16(B + (size_t)(n0 + w * 16 + sr) * 2048 + k0 + sc, &Bs[bsel][(w * 16) * 32]);
        }
    };

    STAGE(0, 0);
    STAGE(1, 32);
    for (int c = 0; c < 64; ++c) {
        const int cur = c % 3;
        if (c < 62) {
            STAGE((c + 2) % 3, (c + 2) * 32);
            if (NT == 128) asm volatile("s_waitcnt vmcnt(8)" ::: "memory");
            else           asm volatile("s_waitcnt vmcnt(6)" ::: "memory");
        } else if (c == 62) {
            if (NT == 128) asm volatile("s_waitcnt vmcnt(4)" ::: "memory");
            else           asm volatile("s_waitcnt vmcnt(3)" ::: "memory");
        } else {
            asm volatile("s_waitcnt vmcnt(0)" ::: "memory");
        }
        __builtin_amdgcn_s_barrier();

        bf16x8 af[MI], bfr[4];
#pragma unroll
        for (int i = 0; i < MI; ++i) af[i]  = *(const bf16x8*)&As[cur][(wm + i * 16 + l16) * 32 + (quad ^ rsw) * 8];
#pragma unroll
        for (int i = 0; i < 4; ++i)  bfr[i] = *(const bf16x8*)&Bs[cur][(wn + i * 16 + l16) * 32 + (quad ^ rsw) * 8];
#pragma unroll
        for (int i = 0; i < MI; ++i)
#pragma unroll
            for (int jn = 0; jn < 4; ++jn)
                acc[i][jn] = __builtin_amdgcn_mfma_f32_16x16x32_bf16(af[i], bfr[jn], acc[i][jn], 0, 0, 0);
        __builtin_amdgcn_s_barrier();
    }

    if (DO_VT && b == 2) {
#pragma unroll
        for (int i = 0; i < MI; ++i)
#pragma unroll
            for (int jn = 0; jn < 4; ++jn) {
                int n = n0 + wn + jn * 16 + l16;
                int m = m0 + wm + i * 16 + quad * 4;
                int sm = (m & ~31) | ((m & 12) << 1) | ((m & 16) >> 2) | (m & 3);
                u16x4 o;
#pragma unroll
                for (int r = 0; r < 4; ++r) o[r] = f2b(acc[i][jn][r]);
                *(u16x4*)&VT[(size_t)n * 2048 + sm] = o;
            }
    } else {
#pragma unroll
        for (int i = 0; i < MI; ++i)
#pragma unroll
            for (int jn = 0; jn < 4; ++jn)
#pragma unroll
                for (int r = 0; r < 4; ++r) {
                    int row = m0 + wm + i * 16 + quad * 4 + r;
                    int col = n0 + wn + jn * 16 + l16;
                    float v = acc[i][jn][r] * alpha;
                    if (OUT_BF16)
                        ((unsigned short*)Cbase + (size_t)b * 4194304)[(size_t)row * 2048 + col] = f2b(v);
                    else
                        ((float*)Cbase)[(size_t)row * 2048 + col] = v;
                }
    }
}

// ---------------- differential flash attention, S^T register path (unchanged) ----------------
__global__ __launch_bounds__(256, 2) void diff_attn(const unsigned short* __restrict__ qb,
                                                    const unsigned short* __restrict__ kb,
                                                    const unsigned short* __restrict__ vt,
                                                    const float* __restrict__ lq1,
                                                    const float* __restrict__ lk1,
                                                    const float* __restrict__ lq2,
                                                    const float* __restrict__ lk2,
                                                    const float* __restrict__ g,
                                                    unsigned short* __restrict__ Aout) {
    __shared__ __align__(16) unsigned short Ks[2][64 * 128];   // [kv][d], 16B-block ^ (row&15) swizzle
    __shared__ __align__(16) unsigned short Vs[2][128 * 64];   // [d][pi(kv)], 16B-block ^ (row&7) swizzle
    __shared__ float lam_s;
    const int tid = threadIdx.x, w = tid >> 6, lane = tid & 63;
    const int quad = lane >> 4, l16 = lane & 15;
    const int bid = blockIdx.x;
    const int wrk = (bid & 7) * 64 + (bid >> 3);   // XCD-contiguous work id
    const int j = wrk >> 5;                        // head-pair 0..15 (2 per XCD)
    const int q0 = (wrk & 31) * 64;                // q-tile

    if (tid < 64) {
        float p1 = lq1[tid] * lk1[tid];
        float p2 = lq2[tid] * lk2[tid];
        for (int off = 32; off; off >>= 1) { p1 += __shfl_xor(p1, off, 64); p2 += __shfl_xor(p2, off, 64); }
        if (tid == 0) lam_s = __expf(p1) - __expf(p2) + LAMBDA_INIT_F;
    }

    bf16x8 qf[2][2];
#pragma unroll
    for (int p = 0; p < 2; ++p)
#pragma unroll
        for (int dh = 0; dh < 2; ++dh)
            qf[p][dh] = *(const bf16x8*)&qb[(size_t)(q0 + w * 16 + l16) * 2048 + j * 128 + p * 64 + dh * 32 + quad * 8];

    f32x4 O[2][8];
#pragma unroll
    for (int p = 0; p < 2; ++p)
#pragma unroll
        for (int i = 0; i < 8; ++i)
#pragma unroll
            for (int r = 0; r < 4; ++r) O[p][i][r] = 0.f;
    float lsum[2] = {0.f, 0.f};

    const int srK = lane >> 4;
    const int srV = lane >> 3;
    const int scV = ((lane & 7) ^ (lane >> 3)) * 8;

    auto STAGE = [&](int bsel, int kv0) {
#pragma unroll
        for (int t = 0; t < 4; ++t) {
            int rowK = w * 16 + t * 4 + srK;
            int cbsK = ((lane & 15) ^ (rowK & 15)) * 8;
            GLD16(kb + (size_t)(kv0 + rowK) * 2048 + j * 128 + cbsK, &Ks[bsel][(w * 16 + t * 4) * 128]);
        }
#pragma unroll
        for (int t = 0; t < 4; ++t) {
            int rowV = w * 32 + t * 8 + srV;
            GLD16(vt + (size_t)(j * 128 + rowV) * 2048 + kv0 + scV, &Vs[bsel][(w * 32 + t * 8) * 64]);
        }
    };

    STAGE(0, 0);
    for (int c = 0; c < 32; ++c) {
        const int cur = c & 1;
        if (c < 31) {
            STAGE(cur ^ 1, (c + 1) * 64);
            asm volatile("s_waitcnt vmcnt(8)" ::: "memory");
        } else {
            asm volatile("s_waitcnt vmcnt(0)" ::: "memory");
        }
        __builtin_amdgcn_s_barrier();

        u32x4 pd[2][2];
#pragma unroll
        for (int p = 0; p < 2; ++p) {
#pragma unroll
            for (int i = 0; i < 4; ++i) {
                bf16x8 a0 = *(const bf16x8*)&Ks[cur][(i * 16 + l16) * 128 + ((p * 8 + quad) ^ l16) * 8];
                bf16x8 a1 = *(const bf16x8*)&Ks[cur][(i * 16 + l16) * 128 + ((p * 8 + 4 + quad) ^ l16) * 8];
                f32x4 s = {0.f, 0.f, 0.f, 0.f};
                s = __builtin_amdgcn_mfma_f32_16x16x32_bf16(a0, qf[p][0], s, 0, 0, 0);
                s = __builtin_amdgcn_mfma_f32_16x16x32_bf16(a1, qf[p][1], s, 0, 0, 0);
                float e0 = EXP2(s[0]), e1 = EXP2(s[1]), e2 = EXP2(s[2]), e3 = EXP2(s[3]);
                lsum[p] += (e0 + e1) + (e2 + e3);
                pd[p][i >> 1][(i & 1) * 2]     = pk2(e0, e1);
                pd[p][i >> 1][(i & 1) * 2 + 1] = pk2(e2, e3);
            }
        }
#pragma unroll
        for (int u = 0; u < 2; ++u) {
            const int blk = (((4 * u + quad) ^ (l16 & 7))) * 8;
#pragma unroll
            for (int dt = 0; dt < 8; ++dt) {
                bf16x8 vf8 = *(const bf16x8*)&Vs[cur][(dt * 16 + l16) * 64 + blk];
                O[0][dt] = __builtin_amdgcn_mfma_f32_16x16x32_bf16(vf8, __builtin_bit_cast(bf16x8, pd[0][u]), O[0][dt], 0, 0, 0);
                O[1][dt] = __builtin_amdgcn_mfma_f32_16x16x32_bf16(vf8, __builtin_bit_cast(bf16x8, pd[1][u]), O[1][dt], 0, 0, 0);
            }
        }
        __builtin_amdgcn_s_barrier();
    }

#pragma unroll
    for (int p = 0; p < 2; ++p) {
        lsum[p] += __shfl_xor(lsum[p], 16, 64);
        lsum[p] += __shfl_xor(lsum[p], 32, 64);
    }
    const float inv1 = 1.0f / lsum[0];
    const float inv2 = lam_s / lsum[1];

    float ssum = 0.f;
#pragma unroll
    for (int dt = 0; dt < 8; ++dt)
#pragma unroll
        for (int r = 0; r < 4; ++r) {
            float v = O[0][dt][r] * inv1 - O[1][dt][r] * inv2;
            O[0][dt][r] = v;
            ssum += v * v;
        }
    ssum += __shfl_xor(ssum, 16, 64);
    ssum += __shfl_xor(ssum, 32, 64);
    const float rms = rsqrtf(ssum * (1.0f / 128.0f) + 1e-5f) * (1.0f - LAMBDA_INIT_F);

#pragma unroll
    for (int dt = 0; dt < 8; ++dt) {
        float4 g4 = *(const float4*)&g[dt * 16 + quad * 4];
        u16x4 o;
        o[0] = f2b(O[0][dt][0] * rms * g4.x);
        o[1] = f2b(O[0][dt][1] * rms * g4.y);
        o[2] = f2b(O[0][dt][2] * rms * g4.z);
        o[3] = f2b(O[0][dt][3] * rms * g4.w);
        *(u16x4*)&Aout[(size_t)(q0 + w * 16 + l16) * 2048 + j * 128 + dt * 16 + quad * 4] = o;
    }
}

extern "C" void kernel_launch(void* const* d_in, const int* in_sizes, int n_in,
                              void* d_out, int out_size, void* d_ws, size_t ws_size,
                              hipStream_t stream) {
    const float* query = (const float*)d_in[0];
    const float* key   = (const float*)d_in[1];
    const float* value = (const float*)d_in[2];
    const float* Wq  = (const float*)d_in[5];
    const float* Wk  = (const float*)d_in[6];
    const float* Wv  = (const float*)d_in[7];
    const float* Wo  = (const float*)d_in[8];
    const float* lq1 = (const float*)d_in[9];
    const float* lk1 = (const float*)d_in[10];
    const float* lq2 = (const float*)d_in[11];
    const float* lk2 = (const float*)d_in[12];
    const float* g   = (const float*)d_in[13];

    char* ws = (char*)d_ws;
    const size_t MB = 1ull << 20;
    const size_t N4 = 4194304;  // 2048*2048
    unsigned short* qb  = (unsigned short*)(ws + 0 * MB);    // qb,kb contiguous (GEMM out z=0,1)
    unsigned short* vt  = (unsigned short*)(ws + 16 * MB);   // V^T (z=2 transposed epilogue, pi-permuted kv)
    unsigned short* Aat = (unsigned short*)(ws + 24 * MB);
    unsigned short* WoB = (unsigned short*)(ws + 32 * MB);   // bf16 Wo (only remaining cvt slab)

    // alpha = HD^-0.5 * log2(e): scores come out in log2 domain -> raw v_exp_f32 in diff_attn
    const float alpha_q = 0.125f * 1.44269504f;

    // only Wo still needs a separate bf16 pass (output projection's B operand)
    cvt7<<<dim3(2048, 1), dim3(256), 0, stream>>>(Wo, Wo, Wo, Wo, Wo, Wo, Wo, WoB);
    // q/k/v projections: 256^2 tiles, 4-phase, f32->bf16 reg-staging (no separate cvt pass)
    gemm_qkv<<<dim3(192), dim3(512), 0, stream>>>(query, key, value, Wq, Wk, Wv, qb, vt, alpha_q);
    diff_attn<<<dim3(512), dim3(256), 0, stream>>>(qb, qb + N4, vt, lq1, lk1, lq2, lk2, g, Aat);
    // output projection: 128x64 tiles -> 512 blocks (2 blocks/CU)
    gemm_bt<0, 64, 0, 2><<<dim3(32, 16, 1), dim3(256), 0, stream>>>(Aat, WoB, d_out, nullptr, 1.0f);
}

// Round 8
// 317.657 us; speedup vs baseline: 1.2348x; 1.2348x over previous
//
#include <hip/hip_runtime.h>
#include <stdint.h>

#define LAMBDA_INIT_F 0.7836057665f   // 0.8 - 0.6*exp(-0.3*12)

typedef __bf16 bf16x8 __attribute__((ext_vector_type(8)));
typedef float  f32x4  __attribute__((ext_vector_type(4)));
typedef unsigned short u16x8 __attribute__((ext_vector_type(8)));
typedef unsigned short u16x4 __attribute__((ext_vector_type(4)));
typedef unsigned int u32x4 __attribute__((ext_vector_type(4)));

__device__ __forceinline__ unsigned short f2b(float f) {
    union { float f; unsigned u; } v; v.f = f;
    unsigned u = v.u;
    return (unsigned short)((u + 0x7fffu + ((u >> 16) & 1u)) >> 16);
}

// pack two fp32 -> two bf16 (round-half-up) in one dword: [bf(b):bf(a)]
__device__ __forceinline__ unsigned pk2(float a, float b) {
    unsigned ua = __float_as_uint(a) + 0x8000u;
    unsigned ub = __float_as_uint(b) + 0x8000u;
    return __builtin_amdgcn_perm(ub, ua, 0x07060302u);
}

#if __has_builtin(__builtin_amdgcn_exp2f)
#define EXP2(x) __builtin_amdgcn_exp2f(x)
#else
__device__ __forceinline__ float EXP2(float x) {
    float r; asm volatile("v_exp_f32 %0, %1\n\ts_nop 1" : "=v"(r) : "v"(x)); return r;
}
#endif

// global(16B/lane) -> LDS direct. LDS base must be wave-uniform; lanes land at base + lane*16.
#define GLD16(gp, sp) __builtin_amdgcn_global_load_lds( \
    (const __attribute__((address_space(1))) void*)(uintptr_t)(gp), \
    (__attribute__((address_space(3))) void*)(uint32_t)(uintptr_t)(sp), 16, 0, 0)

// ---------------- fp32 -> bf16 convert (now only used for Wo, 1 slab) ----------------
__global__ __launch_bounds__(256) void cvt7(const float* __restrict__ s0, const float* __restrict__ s1,
                                            const float* __restrict__ s2, const float* __restrict__ s3,
                                            const float* __restrict__ s4, const float* __restrict__ s5,
                                            const float* __restrict__ s6,
                                            unsigned short* __restrict__ dst) {
    int z = blockIdx.y;
    const float* s = z == 0 ? s0 : z == 1 ? s1 : z == 2 ? s2 : z == 3 ? s3 : z == 4 ? s4 : z == 5 ? s5 : s6;
    unsigned short* d = dst + (size_t)z * 4194304;
    size_t i = ((size_t)blockIdx.x * 256 + threadIdx.x) * 8;
    float4 a = *(const float4*)(s + i);
    float4 b = *(const float4*)(s + i + 4);
    u16x8 o;
    o[0] = f2b(a.x); o[1] = f2b(a.y); o[2] = f2b(a.z); o[3] = f2b(a.w);
    o[4] = f2b(b.x); o[5] = f2b(b.y); o[6] = f2b(b.z); o[7] = f2b(b.w);
    *(u16x8*)(d + i) = o;
}

// ---------------- QKV projection: 256x256, BK=64, 8 waves, 4-phase, spill-free f32 staging ------
// C = alpha * X(f32) @ W(f32)^T per z; z==2 writes C^T to VT (pi-permuted kv).
// Double-buffered LDS (128 KiB, 1 block/CU). Staging rotates quarter-tiles 2 phases deep:
//   A0: issue P1 -> write P3(nxt);  B0: issue P2 -> write P4(nxt);
//   B1: issue P3 -> write next-P1(cur); A1: issue P4 -> write next-P2(cur).
// <=2 halves (32 f32 VGPR) in flight; each load gets ~2 phases of MFMA cover.
// Quadrant order (0,0),(0,1),(1,1),(1,0): one af-group + one b-group live at a time
// (b0 re-read at P4, +4 b128/kt). Live regs ~225 < 256 -> no spill (round-7 lesson).
__global__ __launch_bounds__(512, 1) void gemm_qkv(const float* __restrict__ Qf, const float* __restrict__ Kf,
                                                   const float* __restrict__ Vf, const float* __restrict__ Wqf,
                                                   const float* __restrict__ Wkf, const float* __restrict__ Wvf,
                                                   unsigned short* __restrict__ Cb,
                                                   unsigned short* __restrict__ VT,
                                                   float alpha0) {
    __shared__ __align__(16) unsigned short As[2][16384];   // [buf][kk*8192 + row*32 + col], 64B rows
    __shared__ __align__(16) unsigned short Bs[2][16384];
    const int tid = threadIdx.x;
    const int wid = tid >> 6, lane = tid & 63;
    const int quad = lane >> 4, l16 = lane & 15;
    const int wr = wid >> 2, wc = wid & 3;                 // wave grid 2M x 4N
    const int bid = blockIdx.x;
    const int wrk = (bid & 7) * 24 + (bid >> 3);           // bijective XCD swizzle (192 = 8*24)
    const int z = wrk >> 6;
    const int t6 = wrk & 63;
    const int m0 = (t6 >> 3) * 256, n0 = (t6 & 7) * 256;
    const float* Af = z == 0 ? Qf : z == 1 ? Kf : Vf;
    const float* Bf = z == 0 ? Wqf : z == 1 ? Wkf : Wvf;
    const float alpha = (z == 0) ? alpha0 : 1.0f;

    const int sr = lane >> 2;                              // 0..15 row within 16-row slab
    const int sc = (((lane & 3) ^ ((lane >> 3) & 3)) * 8); // swizzled source colblock (elements)
    const int rsw = ((l16 >> 1) & 3);                      // read-side swizzle key

    f32x4 acc[8][4];
#pragma unroll
    for (int mi = 0; mi < 8; ++mi)
#pragma unroll
        for (int ni = 0; ni < 4; ++ni) acc[mi][ni] = f32x4{0.f, 0.f, 0.f, 0.f};

    // ---- staging helpers: element indices identical to the verified round-7 image ----
    auto LOAD_A = [&](int h, int k0, f32x4 (&R)[2][2]) {
        const int rb = (wid >> 2) * 128 + (wid & 3) * 16 + h * 64;
#pragma unroll
        for (int kk = 0; kk < 2; ++kk) {
            const float* p = Af + (size_t)(m0 + rb + sr) * 2048 + k0 + kk * 32 + sc;
            R[kk][0] = *(const f32x4*)p;
            R[kk][1] = *(const f32x4*)(p + 4);
        }
    };
    auto LOAD_B = [&](int h, int k0, f32x4 (&R)[2][2]) {
        const int rb = (wid >> 1) * 64 + (wid & 1) * 16 + h * 32;
#pragma unroll
        for (int kk = 0; kk < 2; ++kk) {
            const float* p = Bf + (size_t)(n0 + rb + sr) * 2048 + k0 + kk * 32 + sc;
            R[kk][0] = *(const f32x4*)p;
            R[kk][1] = *(const f32x4*)(p + 4);
        }
    };
    auto WR_A = [&](int buf, int h, f32x4 (&R)[2][2]) {
        const int rb = (wid >> 2) * 128 + (wid & 3) * 16 + h * 64;
#pragma unroll
        for (int kk = 0; kk < 2; ++kk) {
            u32x4 o;
            o[0] = pk2(R[kk][0][0], R[kk][0][1]); o[1] = pk2(R[kk][0][2], R[kk][0][3]);
            o[2] = pk2(R[kk][1][0], R[kk][1][1]); o[3] = pk2(R[kk][1][2], R[kk][1][3]);
            *(u32x4*)&As[buf][(kk * 256 + rb) * 32 + lane * 8] = o;   // linear lane*16B (GLD16 image)
        }
    };
    auto WR_B = [&](int buf, int h, f32x4 (&R)[2][2]) {
        const int rb = (wid >> 1) * 64 + (wid & 1) * 16 + h * 32;
#pragma unroll
        for (int kk = 0; kk < 2; ++kk) {
            u32x4 o;
            o[0] = pk2(R[kk][0][0], R[kk][0][1]); o[1] = pk2(R[kk][0][2], R[kk][0][3]);
            o[2] = pk2(R[kk][1][0], R[kk][1][1]); o[3] = pk2(R[kk][1][2], R[kk][1][3]);
            *(u32x4*)&Bs[buf][(kk * 256 + rb) * 32 + lane * 8] = o;
        }
    };

#define LD_A(bf, mh, i, kk) (*(const bf16x8*)&As[bf][(kk * 256 + wr * 128 + (mh) * 64 + (i) * 16 + l16) * 32 + (quad ^ rsw) * 8])
#define LD_B(bf, nh, jn, kk) (*(const bf16x8*)&Bs[bf][(kk * 256 + wc * 64 + (nh) * 32 + (jn) * 16 + l16) * 32 + (quad ^ rsw) * 8])
#define LGKM0 asm volatile("s_waitcnt lgkmcnt(0)" ::: "memory")
#define BAR   __builtin_amdgcn_s_barrier()

    // staged-value registers (persist across phases / iterations)
    f32x4 vA0[2][2], vB0[2][2], vB1[2][2], vA1[2][2];

    // prologue: tile 0 -> buf 0 (one-shot load+pack+write)
    LOAD_A(0, 0, vA0); LOAD_B(0, 0, vB0); LOAD_B(1, 0, vB1); LOAD_A(1, 0, vA1);
    WR_A(0, 0, vA0); WR_B(0, 0, vB0); WR_B(0, 1, vB1); WR_A(0, 1, vA1);
    LGKM0;
    BAR;

    for (int kt = 0; kt < 32; ++kt) {
        const int cur = kt & 1, nxt = cur ^ 1;
        const int k1 = (kt + 1) * 64;
        bf16x8 a0f[2][4], bb[2][2];

        // ---- P1: write B1(kt)->cur [issued prev P3]; issue A0(kt+1); ds_read af0,b0; MFMA (0,0)
        if (kt > 0) WR_B(cur, 1, vB1);
        if (kt < 31) LOAD_A(0, k1, vA0);
#pragma unroll
        for (int kk = 0; kk < 2; ++kk) {
#pragma unroll
            for (int i = 0; i < 4; ++i) a0f[kk][i] = LD_A(cur, 0, i, kk);
#pragma unroll
            for (int jn = 0; jn < 2; ++jn) bb[kk][jn] = LD_B(cur, 0, jn, kk);
        }
        LGKM0;
        BAR;
        __builtin_amdgcn_s_setprio(1);
#pragma unroll
        for (int i = 0; i < 4; ++i)
#pragma unroll
            for (int jn = 0; jn < 2; ++jn)
#pragma unroll
                for (int kk = 0; kk < 2; ++kk)
                    acc[i][jn] = __builtin_amdgcn_mfma_f32_16x16x32_bf16(a0f[kk][i], bb[kk][jn], acc[i][jn], 0, 0, 0);
        __builtin_amdgcn_s_setprio(0);
        BAR;

        // ---- P2: write A1(kt)->cur [issued prev P4]; issue B0(kt+1); ds_read b1; MFMA (0,1)
        if (kt > 0) WR_A(cur, 1, vA1);
        if (kt < 31) LOAD_B(0, k1, vB0);
#pragma unroll
        for (int kk = 0; kk < 2; ++kk)
#pragma unroll
            for (int jn = 0; jn < 2; ++jn) bb[kk][jn] = LD_B(cur, 1, jn, kk);
        LGKM0;
        BAR;
        __builtin_amdgcn_s_setprio(1);
#pragma unroll
        for (int i = 0; i < 4; ++i)
#pragma unroll
            for (int jn = 0; jn < 2; ++jn)
#pragma unroll
                for (int kk = 0; kk < 2; ++kk)
                    acc[i][2 + jn] = __builtin_amdgcn_mfma_f32_16x16x32_bf16(a0f[kk][i], bb[kk][jn], acc[i][2 + jn], 0, 0, 0);
        __builtin_amdgcn_s_setprio(0);
        BAR;

        // ---- P3: write A0(kt+1)->nxt [issued P1]; issue B1(kt+1); ds_read af1; MFMA (1,1)
        if (kt < 31) { WR_A(nxt, 0, vA0); LOAD_B(1, k1, vB1); }
#pragma unroll
        for (int kk = 0; kk < 2; ++kk)
#pragma unroll
            for (int i = 0; i < 4; ++i) a0f[kk][i] = LD_A(cur, 1, i, kk);
        LGKM0;
        BAR;
        __builtin_amdgcn_s_setprio(1);
#pragma unroll
        for (int i = 0; i < 4; ++i)
#pragma unroll
            for (int jn = 0; jn < 2; ++jn)
#pragma unroll
                for (int kk = 0; kk < 2; ++kk)
                    acc[4 + i][2 + jn] = __builtin_amdgcn_mfma_f32_16x16x32_bf16(a0f[kk][i], bb[kk][jn], acc[4 + i][2 + jn], 0, 0, 0);
        __builtin_amdgcn_s_setprio(0);
        BAR;

        // ---- P4: write B0(kt+1)->nxt [issued P2]; issue A1(kt+1); re-read b0; MFMA (1,0)
        if (kt < 31) { WR_B(nxt, 0, vB0); LOAD_A(1, k1, vA1); }
#pragma unroll
        for (int kk = 0; kk < 2; ++kk)
#pragma unroll
            for (int jn = 0; jn < 2; ++jn) bb[kk][jn] = LD_B(cur, 0, jn, kk);
        LGKM0;
        BAR;
        __builtin_amdgcn_s_setprio(1);
#pragma unroll
        for (int i = 0; i < 4; ++i)
#pragma unroll
            for (int jn = 0; jn < 2; ++jn)
#pragma unroll
                for (int kk = 0; kk < 2; ++kk)
                    acc[4 + i][jn] = __builtin_amdgcn_mfma_f32_16x16x32_bf16(a0f[kk][i], bb[kk][jn], acc[4 + i][jn], 0, 0, 0);
        __builtin_amdgcn_s_setprio(0);
        BAR;
    }
#undef LD_A
#undef LD_B
#undef LGKM0
#undef BAR

    if (z == 2) {
        // transposed write: VT[n][pi(m)], packed 4 bf16 (m-consecutive, pi keeps low 2 bits)
#pragma unroll
        for (int mi = 0; mi < 8; ++mi)
#pragma unroll
            for (int ni = 0; ni < 4; ++ni) {
                int n = n0 + wc * 64 + ni * 16 + l16;
                int m = m0 + wr * 128 + mi * 16 + quad * 4;
                int sm = (m & ~31) | ((m & 12) << 1) | ((m & 16) >> 2) | (m & 3);
                u16x4 o;
#pragma unroll
                for (int r = 0; r < 4; ++r) o[r] = f2b(acc[mi][ni][r]);
                *(u16x4*)&VT[(size_t)n * 2048 + sm] = o;
            }
    } else {
        unsigned short* Cz = Cb + (size_t)z * 4194304;
#pragma unroll
        for (int mi = 0; mi < 8; ++mi)
#pragma unroll
            for (int ni = 0; ni < 4; ++ni)
#pragma unroll
                for (int r = 0; r < 4; ++r) {
                    int row = m0 + wr * 128 + mi * 16 + quad * 4 + r;
                    int col = n0 + wc * 64 + ni * 16 + l16;
                    Cz[(size_t)row * 2048 + col] = f2b(acc[mi][ni][r] * alpha);
                }
    }
}

// ---------------- output projection: 128x64 tiles, triple-buffered (unchanged) ----------------
template <int OUT_BF16, int NT, int DO_VT, int WPB>
__global__ __launch_bounds__(256, WPB) void gemm_bt(const unsigned short* __restrict__ Abase,
                                                    const unsigned short* __restrict__ Bbase,
                                                    void* __restrict__ Cbase,
                                                    unsigned short* __restrict__ VT,
                                                    float alpha0) {
    constexpr int MI = (NT == 128) ? 4 : 2;
    __shared__ __align__(16) unsigned short As[3][128 * 32];
    __shared__ __align__(16) unsigned short Bs[3][NT * 32];
    const int tid = threadIdx.x;
    const int w = tid >> 6, lane = tid & 63;
    const int quad = lane >> 4, l16 = lane & 15;
    const int b = blockIdx.z;
    const unsigned short* A = Abase + (size_t)b * 4194304;
    const unsigned short* B = Bbase + (size_t)b * 4194304;
    const float alpha = (b == 0) ? alpha0 : 1.0f;
    const int m0 = blockIdx.y * 128, n0 = blockIdx.x * NT;
    const int wm = (NT == 128) ? (w >> 1) * 64 : w * 32;
    const int wn = (NT == 128) ? (w & 1) * 64 : 0;
    const int sr = lane >> 2;                              // 0..15 row within 16-row slab
    const int sc = (((lane & 3) ^ ((lane >> 3) & 3)) * 8); // swizzled global colblock
    const int rsw = ((l16 >> 1) & 3);                      // read-side swizzle key

    f32x4 zz = {0.f, 0.f, 0.f, 0.f};
    f32x4 acc[MI][4];
#pragma unroll
    for (int i = 0; i < MI; ++i)
#pragma unroll
        for (int jn = 0; jn < 4; ++jn) acc[i][jn] = zz;

    auto STAGE = [&](int bsel, int k0) {
        GLD16(A + (size_t)(m0 + w * 16 + sr) * 2048 + k0 + sc,      &As[bsel][(w * 16) * 32]);
        GLD16(A + (size_t)(m0 + 64 + w * 16 + sr) * 2048 + k0 + sc, &As[bsel][(64 + w * 16) * 32]);
        if (NT == 128) {
            GLD16(B + (size_t)(n0 + w * 16 + sr) * 2048 + k0 + sc,      &Bs[bsel][(w * 16) * 32]);
            GLD16(B + (size_t)(n0 + 64 + w * 16 + sr) * 2048 + k0 + sc, &Bs[bsel][(64 + w * 16) * 32]);
        } else {
            GLD16(B + (size_t)(n0 + w * 16 + sr) * 2048 + k0 + sc, &Bs[bsel][(w * 16) * 32]);
        }
    };

    STAGE(0, 0);
    STAGE(1, 32);
    for (int c = 0; c < 64; ++c) {
        const int cur = c % 3;
        if (c < 62) {
            STAGE((c + 2) % 3, (c + 2) * 32);
            if (NT == 128) asm volatile("s_waitcnt vmcnt(8)" ::: "memory");
            else           asm volatile("s_waitcnt vmcnt(6)" ::: "memory");
        } else if (c == 62) {
            if (NT == 128) asm volatile("s_waitcnt vmcnt(4)" ::: "memory");
            else           asm volatile("s_waitcnt vmcnt(3)" ::: "memory");
        } else {
            asm volatile("s_waitcnt vmcnt(0)" ::: "memory");
        }
        __builtin_amdgcn_s_barrier();

        bf16x8 af[MI], bfr[4];
#pragma unroll
        for (int i = 0; i < MI; ++i) af[i]  = *(const bf16x8*)&As[cur][(wm + i * 16 + l16) * 32 + (quad ^ rsw) * 8];
#pragma unroll
        for (int i = 0; i < 4; ++i)  bfr[i] = *(const bf16x8*)&Bs[cur][(wn + i * 16 + l16) * 32 + (quad ^ rsw) * 8];
#pragma unroll
        for (int i = 0; i < MI; ++i)
#pragma unroll
            for (int jn = 0; jn < 4; ++jn)
                acc[i][jn] = __builtin_amdgcn_mfma_f32_16x16x32_bf16(af[i], bfr[jn], acc[i][jn], 0, 0, 0);
        __builtin_amdgcn_s_barrier();
    }

    if (DO_VT && b == 2) {
#pragma unroll
        for (int i = 0; i < MI; ++i)
#pragma unroll
            for (int jn = 0; jn < 4; ++jn) {
                int n = n0 + wn + jn * 16 + l16;
                int m = m0 + wm + i * 16 + quad * 4;
                int sm = (m & ~31) | ((m & 12) << 1) | ((m & 16) >> 2) | (m & 3);
                u16x4 o;
#pragma unroll
                for (int r = 0; r < 4; ++r) o[r] = f2b(acc[i][jn][r]);
                *(u16x4*)&VT[(size_t)n * 2048 + sm] = o;
            }
    } else {
#pragma unroll
        for (int i = 0; i < MI; ++i)
#pragma unroll
            for (int jn = 0; jn < 4; ++jn)
#pragma unroll
                for (int r = 0; r < 4; ++r) {
                    int row = m0 + wm + i * 16 + quad * 4 + r;
                    int col = n0 + wn + jn * 16 + l16;
                    float v = acc[i][jn][r] * alpha;
                    if (OUT_BF16)
                        ((unsigned short*)Cbase + (size_t)b * 4194304)[(size_t)row * 2048 + col] = f2b(v);
                    else
                        ((float*)Cbase)[(size_t)row * 2048 + col] = v;
                }
    }
}

// ---------------- differential flash attention, S^T register path (unchanged) ----------------
__global__ __launch_bounds__(256, 2) void diff_attn(const unsigned short* __restrict__ qb,
                                                    const unsigned short* __restrict__ kb,
                                                    const unsigned short* __restrict__ vt,
                                                    const float* __restrict__ lq1,
                                                    const float* __restrict__ lk1,
                                                    const float* __restrict__ lq2,
                                                    const float* __restrict__ lk2,
                                                    const float* __restrict__ g,
                                                    unsigned short* __restrict__ Aout) {
    __shared__ __align__(16) unsigned short Ks[2][64 * 128];   // [kv][d], 16B-block ^ (row&15) swizzle
    __shared__ __align__(16) unsigned short Vs[2][128 * 64];   // [d][pi(kv)], 16B-block ^ (row&7) swizzle
    __shared__ float lam_s;
    const int tid = threadIdx.x, w = tid >> 6, lane = tid & 63;
    const int quad = lane >> 4, l16 = lane & 15;
    const int bid = blockIdx.x;
    const int wrk = (bid & 7) * 64 + (bid >> 3);   // XCD-contiguous work id
    const int j = wrk >> 5;                        // head-pair 0..15 (2 per XCD)
    const int q0 = (wrk & 31) * 64;                // q-tile

    if (tid < 64) {
        float p1 = lq1[tid] * lk1[tid];
        float p2 = lq2[tid] * lk2[tid];
        for (int off = 32; off; off >>= 1) { p1 += __shfl_xor(p1, off, 64); p2 += __shfl_xor(p2, off, 64); }
        if (tid == 0) lam_s = __expf(p1) - __expf(p2) + LAMBDA_INIT_F;
    }

    bf16x8 qf[2][2];
#pragma unroll
    for (int p = 0; p < 2; ++p)
#pragma unroll
        for (int dh = 0; dh < 2; ++dh)
            qf[p][dh] = *(const bf16x8*)&qb[(size_t)(q0 + w * 16 + l16) * 2048 + j * 128 + p * 64 + dh * 32 + quad * 8];

    f32x4 O[2][8];
#pragma unroll
    for (int p = 0; p < 2; ++p)
#pragma unroll
        for (int i = 0; i < 8; ++i)
#pragma unroll
            for (int r = 0; r < 4; ++r) O[p][i][r] = 0.f;
    float lsum[2] = {0.f, 0.f};

    const int srK = lane >> 4;
    const int srV = lane >> 3;
    const int scV = ((lane & 7) ^ (lane >> 3)) * 8;

    auto STAGE = [&](int bsel, int kv0) {
#pragma unroll
        for (int t = 0; t < 4; ++t) {
            int rowK = w * 16 + t * 4 + srK;
            int cbsK = ((lane & 15) ^ (rowK & 15)) * 8;
            GLD16(kb + (size_t)(kv0 + rowK) * 2048 + j * 128 + cbsK, &Ks[bsel][(w * 16 + t * 4) * 128]);
        }
#pragma unroll
        for (int t = 0; t < 4; ++t) {
            int rowV = w * 32 + t * 8 + srV;
            GLD16(vt + (size_t)(j * 128 + rowV) * 2048 + kv0 + scV, &Vs[bsel][(w * 32 + t * 8) * 64]);
        }
    };

    STAGE(0, 0);
    for (int c = 0; c < 32; ++c) {
        const int cur = c & 1;
        if (c < 31) {
            STAGE(cur ^ 1, (c + 1) * 64);
            asm volatile("s_waitcnt vmcnt(8)" ::: "memory");
        } else {
            asm volatile("s_waitcnt vmcnt(0)" ::: "memory");
        }
        __builtin_amdgcn_s_barrier();

        u32x4 pd[2][2];
#pragma unroll
        for (int p = 0; p < 2; ++p) {
#pragma unroll
            for (int i = 0; i < 4; ++i) {
                bf16x8 a0 = *(const bf16x8*)&Ks[cur][(i * 16 + l16) * 128 + ((p * 8 + quad) ^ l16) * 8];
                bf16x8 a1 = *(const bf16x8*)&Ks[cur][(i * 16 + l16) * 128 + ((p * 8 + 4 + quad) ^ l16) * 8];
                f32x4 s = {0.f, 0.f, 0.f, 0.f};
                s = __builtin_amdgcn_mfma_f32_16x16x32_bf16(a0, qf[p][0], s, 0, 0, 0);
                s = __builtin_amdgcn_mfma_f32_16x16x32_bf16(a1, qf[p][1], s, 0, 0, 0);
                float e0 = EXP2(s[0]), e1 = EXP2(s[1]), e2 = EXP2(s[2]), e3 = EXP2(s[3]);
                lsum[p] += (e0 + e1) + (e2 + e3);
                pd[p][i >> 1][(i & 1) * 2]     = pk2(e0, e1);
                pd[p][i >> 1][(i & 1) * 2 + 1] = pk2(e2, e3);
            }
        }
#pragma unroll
        for (int u = 0; u < 2; ++u) {
            const int blk = (((4 * u + quad) ^ (l16 & 7))) * 8;
#pragma unroll
            for (int dt = 0; dt < 8; ++dt) {
                bf16x8 vf8 = *(const bf16x8*)&Vs[cur][(dt * 16 + l16) * 64 + blk];
                O[0][dt] = __builtin_amdgcn_mfma_f32_16x16x32_bf16(vf8, __builtin_bit_cast(bf16x8, pd[0][u]), O[0][dt], 0, 0, 0);
                O[1][dt] = __builtin_amdgcn_mfma_f32_16x16x32_bf16(vf8, __builtin_bit_cast(bf16x8, pd[1][u]), O[1][dt], 0, 0, 0);
            }
        }
        __builtin_amdgcn_s_barrier();
    }

#pragma unroll
    for (int p = 0; p < 2; ++p) {
        lsum[p] += __shfl_xor(lsum[p], 16, 64);
        lsum[p] += __shfl_xor(lsum[p], 32, 64);
    }
    const float inv1 = 1.0f / lsum[0];
    const float inv2 = lam_s / lsum[1];

    float ssum = 0.f;
#pragma unroll
    for (int dt = 0; dt < 8; ++dt)
#pragma unroll
        for (int r = 0; r < 4; ++r) {
            float v = O[0][dt][r] * inv1 - O[1][dt][r] * inv2;
            O[0][dt][r] = v;
            ssum += v * v;
        }
    ssum += __shfl_xor(ssum, 16, 64);
    ssum += __shfl_xor(ssum, 32, 64);
    const float rms = rsqrtf(ssum * (1.0f / 128.0f) + 1e-5f) * (1.0f - LAMBDA_INIT_F);

#pragma unroll
    for (int dt = 0; dt < 8; ++dt) {
        float4 g4 = *(const float4*)&g[dt * 16 + quad * 4];
        u16x4 o;
        o[0] = f2b(O[0][dt][0] * rms * g4.x);
        o[1] = f2b(O[0][dt][1] * rms * g4.y);
        o[2] = f2b(O[0][dt][2] * rms * g4.z);
        o[3] = f2b(O[0][dt][3] * rms * g4.w);
        *(u16x4*)&Aout[(size_t)(q0 + w * 16 + l16) * 2048 + j * 128 + dt * 16 + quad * 4] = o;
    }
}

extern "C" void kernel_launch(void* const* d_in, const int* in_sizes, int n_in,
                              void* d_out, int out_size, void* d_ws, size_t ws_size,
                              hipStream_t stream) {
    const float* query = (const float*)d_in[0];
    const float* key   = (const float*)d_in[1];
    const float* value = (const float*)d_in[2];
    const float* Wq  = (const float*)d_in[5];
    const float* Wk  = (const float*)d_in[6];
    const float* Wv  = (const float*)d_in[7];
    const float* Wo  = (const float*)d_in[8];
    const float* lq1 = (const float*)d_in[9];
    const float* lk1 = (const float*)d_in[10];
    const float* lq2 = (const float*)d_in[11];
    const float* lk2 = (const float*)d_in[12];
    const float* g   = (const float*)d_in[13];

    char* ws = (char*)d_ws;
    const size_t MB = 1ull << 20;
    const size_t N4 = 4194304;  // 2048*2048
    unsigned short* qb  = (unsigned short*)(ws + 0 * MB);    // qb,kb contiguous (GEMM out z=0,1)
    unsigned short* vt  = (unsigned short*)(ws + 16 * MB);   // V^T (z=2 transposed epilogue, pi-permuted kv)
    unsigned short* Aat = (unsigned short*)(ws + 24 * MB);
    unsigned short* WoB = (unsigned short*)(ws + 32 * MB);   // bf16 Wo (only remaining cvt slab)

    // alpha = HD^-0.5 * log2(e): scores come out in log2 domain -> raw v_exp_f32 in diff_attn
    const float alpha_q = 0.125f * 1.44269504f;

    // only Wo still needs a separate bf16 pass (output projection's B operand)
    cvt7<<<dim3(2048, 1), dim3(256), 0, stream>>>(Wo, Wo, Wo, Wo, Wo, Wo, Wo, WoB);
    // q/k/v projections: 256^2 tiles, 4-phase, spill-free staggered f32->bf16 staging
    gemm_qkv<<<dim3(192), dim3(512), 0, stream>>>(query, key, value, Wq, Wk, Wv, qb, vt, alpha_q);
    diff_attn<<<dim3(512), dim3(256), 0, stream>>>(qb, qb + N4, vt, lq1, lk1, lq2, lk2, g, Aat);
    // output projection: 128x64 tiles -> 512 blocks (2 blocks/CU)
    gemm_bt<0, 64, 0, 2><<<dim3(32, 16, 1), dim3(256), 0, stream>>>(Aat, WoB, d_out, nullptr, 1.0f);
}